// Round 2
// baseline (423.221 us; speedup 1.0000x reference)
//
#include <hip/hip_runtime.h>

#define NB 32
#define NS 2048
#define ND 512
#define NA 64
#define NE 64

typedef __bf16 bf16x8 __attribute__((ext_vector_type(8)));
typedef float f32x4 __attribute__((ext_vector_type(4)));

__device__ __forceinline__ unsigned short f2bf(float f) {
    union { float f; unsigned u; } v; v.f = f;
    unsigned r = (v.u + 0x7fffu + ((v.u >> 16) & 1u)) >> 16;
    return (unsigned short)r;
}
__device__ __forceinline__ unsigned pk(float a, float b) {
    return (unsigned)f2bf(a) | ((unsigned)f2bf(b) << 16);
}

// ---------------------------------------------------------------------------
// Kernel 1b (runs FIRST): the six small per-sample vectors, per b:
// [pre_w 512][pre_b 512][post_w 512][post_b 512][b_up 512][b_down 64] = 2624
// ---------------------------------------------------------------------------
__global__ __launch_bounds__(256) void hyper_vec(
    const float* __restrict__ emb,
    const float* __restrict__ pwW, const float* __restrict__ pwb,
    const float* __restrict__ pbW, const float* __restrict__ pbb,
    const float* __restrict__ powW, const float* __restrict__ powb,
    const float* __restrict__ pobW, const float* __restrict__ pobb,
    const float* __restrict__ ubW, const float* __restrict__ ubb,
    const float* __restrict__ dbW, const float* __restrict__ dbb,
    float* __restrict__ vecs) {
    int gid = blockIdx.x * 256 + threadIdx.x;
    if (gid >= NB * 2624) return;
    int b = gid / 2624;
    int r = gid - b * 2624;
    const float* W; const float* bias; int off, width;
    if (r < 2560) {
        int v = r >> 9; off = r & 511; width = 512;
        switch (v) {
            case 0:  W = pwW;  bias = pwb;  break;
            case 1:  W = pbW;  bias = pbb;  break;
            case 2:  W = powW; bias = powb; break;
            case 3:  W = pobW; bias = pobb; break;
            default: W = ubW;  bias = ubb;  break;
        }
    } else {
        off = r - 2560; width = 64; W = dbW; bias = dbb;
    }
    float acc = bias[off];
    const float* e = emb + b * 64;
#pragma unroll 8
    for (int k = 0; k < 64; ++k) acc = fmaf(e[k], W[k * width + off], acc);
    vecs[gid] = acc;
}

// ---------------------------------------------------------------------------
// Kernel 1a: hypernet big GEMMs emb[32,64] @ W[64,32768] -> bf16 frags.
// mat==0 (down): fold pre-LN weight in-line (f = raw*pre_w), emit folded
//   frags [b][nt(4)][kc(16)][lane(64)][8] and atomically accumulate
//   c1[b,a]=sum_d raw*pre_b, c2[b,a]=sum_d raw*pre_w into cvec[b][a][2].
// mat==1 (up): frags [b][nblk(32)][kch(2)][lane(64)][8].
// ---------------------------------------------------------------------------
__global__ __launch_bounds__(256) void hyper_pack(
    const float* __restrict__ emb,
    const float* __restrict__ dwW, const float* __restrict__ dwb,
    const float* __restrict__ uwW, const float* __restrict__ uwb,
    const float* __restrict__ vecs,
    unsigned short* __restrict__ wdfrag, unsigned short* __restrict__ wufrag,
    float* __restrict__ cvec) {
    __shared__ float Wt[64][128];
    __shared__ float embs[NB * NE];
    const int tid = threadIdx.x;
    const int lane = tid & 63;
    const int bx = blockIdx.x;
    const int mat = bx >> 8;
    const int chunk = bx & 255;
    const int base = chunk * 128;
    const int colo = tid & 127;
    const int bh = tid >> 7;            // 0 or 1: b-range [16*bh, 16*bh+16)
    const float* W = mat ? uwW : dwW;
    const float* bias = mat ? uwb : dwb;

    for (int i = tid; i < NB * NE; i += 256) embs[i] = emb[i];
    for (int i = tid; i < 64 * 32; i += 256) {
        int k = i >> 5, c = (i & 31) << 2;
        *(float4*)&Wt[k][c] = *(const float4*)&W[(size_t)k * 32768 + base + c];
    }
    __syncthreads();

    const int col = base + colo;
    const float bv = bias[col];
    float acc[16];
#pragma unroll
    for (int b = 0; b < 16; ++b) acc[b] = bv;

    for (int k0 = 0; k0 < 64; k0 += 4) {
        float w0 = Wt[k0][colo], w1 = Wt[k0 + 1][colo];
        float w2 = Wt[k0 + 2][colo], w3 = Wt[k0 + 3][colo];
#pragma unroll
        for (int b = 0; b < 16; ++b) {
            float4 e = *(const float4*)&embs[(bh * 16 + b) * 64 + k0];
            acc[b] = fmaf(e.x, w0, acc[b]);
            acc[b] = fmaf(e.y, w1, acc[b]);
            acc[b] = fmaf(e.z, w2, acc[b]);
            acc[b] = fmaf(e.w, w3, acc[b]);
        }
    }

    if (mat == 0) {
        int a = col >> 9, d = col & 511;   // a uniform per block (128 | 512)
        size_t idx0 = ((size_t)((a >> 4) * 16 + (d >> 5)) * 64 +
                       (((d & 31) >> 3) * 16 + (a & 15))) * 8 + (d & 7);
#pragma unroll
        for (int b = 0; b < 16; ++b) {
            int bg = bh * 16 + b;
            float raw = acc[b];
            float pw = vecs[bg * 2624 + d];
            float pb = vecs[bg * 2624 + 512 + d];
            float f = raw * pw;
            wdfrag[idx0 + (size_t)bg * 32768] = f2bf(f);
            float c2v = f, c1v = raw * pb;
#pragma unroll
            for (int m = 1; m <= 32; m <<= 1) {
                c2v += __shfl_xor(c2v, m);
                c1v += __shfl_xor(c1v, m);
            }
            if (lane == 0) {
                atomicAdd(&cvec[bg * 128 + 2 * a], c1v);
                atomicAdd(&cvec[bg * 128 + 2 * a + 1], c2v);
            }
        }
    } else {
        int d = col >> 6, a = col & 63;
        size_t idx0 = ((size_t)((d >> 4) * 2 + (a >> 5)) * 64 +
                       (((a & 31) >> 3) * 16 + (d & 15))) * 8 + (a & 7);
#pragma unroll
        for (int b = 0; b < 16; ++b)
            wufrag[idx0 + (size_t)(bh * 16 + b) * 32768] = f2bf(acc[b]);
    }
}

// ---------------------------------------------------------------------------
// Kernel 2: fused [foldedLN + down MFMA] -> relu -> up (MFMA, col-split) ->
// postLN -> +x.
//
// Round-2 restructure: 1024 blocks (exactly 4/CU, zero tail), each block owns
// 64 rows of one b = 4 sequential 16-row tiles.  Per-tile datapath is the
// measured-fastest z_lds structure.  Three changes vs the 4096-block version:
//   (a) weights/coeff/cvec fetched or hoisted ONCE per block, reused 4x;
//   (b) tile t+1's input (8 float4/thread) is prefetched during tile t's
//       phase A and consumed a full tile later (~2500 cy of cover);
//   (c) all __syncthreads() replaced by raw {s_waitcnt lgkmcnt(0); s_barrier}
//       so the prefetch's vmcnt stays OUTSTANDING across barriers (the
//       compiler's __syncthreads lowering drains vmcnt(0), which would
//       expose full HBM latency every tile).
// Cross-tile WAR hazards: every LDS buffer reuse is separated by >=2 raw
// barriers, and each wave drains lgkmcnt(0) before every barrier, so all
// reads of tile t's data complete before any wave can write tile t+1's.
// ---------------------------------------------------------------------------
__global__ __launch_bounds__(256, 4) void fused_adapter(
    const float* __restrict__ inp,
    const unsigned short* __restrict__ wdfold,
    const unsigned short* __restrict__ wufrag,
    const float* __restrict__ vecs,
    const float* __restrict__ cvec,
    float* __restrict__ out) {
    __shared__ __align__(16) unsigned short z_lds[16][520];
    __shared__ __align__(16) unsigned short mid_lds[16][72];
    __shared__ __align__(16) float coeff[1536];  // post_w | post_b | b_up
    __shared__ __align__(16) float preS[16][4], preQ[16][4];
    __shared__ __align__(16) float postS[16][4], postQ[16][4];

    const int tid = threadIdx.x;
    const int lane = tid & 63;
    const int wave = tid >> 6;
    const int lanelo = lane & 15;
    const int quad = lane >> 4;
    // bijective XCD swizzle: 1024 blocks -> XCD x gets contiguous [128x,128x+128)
    // = 4 b's per XCD, so the 4x128 KB of adapter weights are XCD-L2-resident.
    const int bx0 = blockIdx.x;
    const int bx = (bx0 & 7) * 128 + (bx0 >> 3);
    const int b = bx >> 5;
    const int s_base = (bx & 31) * 64;   // 64 rows per block

    // ---- issue tile-0 input loads first (longest latency) ----
    const float* xpw = inp + ((size_t)b * NS + s_base + lanelo) * ND + wave * 128 + quad * 8;
    float4 x0[4], x1[4];
#pragma unroll
    for (int kc2 = 0; kc2 < 4; ++kc2) {
        x0[kc2] = *(const float4*)(xpw + kc2 * 32);
        x1[kc2] = *(const float4*)(xpw + kc2 * 32 + 4);
    }

    const float* vb = vecs + b * 2624;
    for (int i = tid; i < 384; i += 256)
        ((float4*)coeff)[i] = ((const float4*)(vb + 1024))[i];

    // per-block invariants (reused all 4 tiles)
    const unsigned short* wd = wdfold + (size_t)b * 32768;
    const unsigned short* wu = wufrag + (size_t)b * 32768;
    const int a_col = wave * 16 + lanelo;
    const float2 cc = *(const float2*)(cvec + b * 128 + 2 * a_col);
    const float c1 = cc.x + vb[2560 + a_col];

    for (int t = 0; t < 4; ++t) {
        // ---- phase A: stats + bf16 pack + z_lds stage (from registers) ----
        float s = 0.f, q = 0.f;
#pragma unroll
        for (int kc2 = 0; kc2 < 4; ++kc2) {
            float4 a = x0[kc2], c = x1[kc2];
            s += (a.x + a.y + a.z + a.w) + (c.x + c.y + c.z + c.w);
            q = fmaf(a.x, a.x, q); q = fmaf(a.y, a.y, q);
            q = fmaf(a.z, a.z, q); q = fmaf(a.w, a.w, q);
            q = fmaf(c.x, c.x, q); q = fmaf(c.y, c.y, q);
            q = fmaf(c.z, c.z, q); q = fmaf(c.w, c.w, q);
            uint4 au;
            au.x = pk(a.x, a.y); au.y = pk(a.z, a.w);
            au.z = pk(c.x, c.y); au.w = pk(c.z, c.w);
            *(uint4*)&z_lds[lanelo][wave * 128 + kc2 * 32 + quad * 8] = au;
        }
        s += __shfl_xor(s, 16); s += __shfl_xor(s, 32);
        q += __shfl_xor(q, 16); q += __shfl_xor(q, 32);
        if (lane < 16) { preS[lane][wave] = s; preQ[lane][wave] = q; }

        // ---- prefetch tile t+1 input; stays in flight across barriers ----
        if (t < 3) {
            const float* xn = xpw + (size_t)(t + 1) * 16 * ND;
#pragma unroll
            for (int kc2 = 0; kc2 < 4; ++kc2) {
                x0[kc2] = *(const float4*)(xn + kc2 * 32);
                x1[kc2] = *(const float4*)(xn + kc2 * 32 + 4);
            }
        }
        asm volatile("s_waitcnt lgkmcnt(0)" ::: "memory");
        __builtin_amdgcn_s_barrier();   // z + pre-stat partials (+coeff) visible

        float rs[4], mrs[4];
#pragma unroll
        for (int r = 0; r < 4; ++r) {
            int row = quad * 4 + r;
            float4 S = *(const float4*)preS[row];
            float4 Q = *(const float4*)preQ[row];
            float ss = (S.x + S.y) + (S.z + S.w);
            float qq = (Q.x + Q.y) + (Q.z + Q.w);
            float mean = ss * (1.0f / 512.0f);
            float var = qq * (1.0f / 512.0f) - mean * mean;
            float rstd = rsqrtf(var + 1e-5f);
            rs[r] = rstd;
            mrs[r] = mean * rstd;
        }

        // ---- phase B: down GEMM, nt = wave ----
        f32x4 accd = (f32x4){0.f, 0.f, 0.f, 0.f};
#pragma unroll
        for (int kc = 0; kc < 16; ++kc) {
            uint4 azu = *(const uint4*)&z_lds[lanelo][kc * 32 + quad * 8];
            uint4 bu = *(const uint4*)(wd + ((size_t)(wave * 16 + kc) * 64 + lane) * 8);
            accd = __builtin_amdgcn_mfma_f32_16x16x32_bf16(
                __builtin_bit_cast(bf16x8, azu), __builtin_bit_cast(bf16x8, bu), accd, 0, 0, 0);
        }
#pragma unroll
        for (int r = 0; r < 4; ++r) {
            float v = fmaf(rs[r], accd[r], fmaf(-mrs[r], cc.y, c1));
            mid_lds[quad * 4 + r][a_col] = f2bf(fmaxf(v, 0.0f));
        }
        asm volatile("s_waitcnt lgkmcnt(0)" ::: "memory");
        __builtin_amdgcn_s_barrier();   // mid visible

        // ---- phase C: up GEMM, wave w -> cols [128w,128w+128), acc[8] ----
        uint4 a0u = *(const uint4*)&mid_lds[lanelo][quad * 8];
        uint4 a1u = *(const uint4*)&mid_lds[lanelo][32 + quad * 8];
        bf16x8 af0 = __builtin_bit_cast(bf16x8, a0u);
        bf16x8 af1 = __builtin_bit_cast(bf16x8, a1u);
        f32x4 acc8[8];
        float sum[4] = {0.f, 0.f, 0.f, 0.f}, sq[4] = {0.f, 0.f, 0.f, 0.f};
#pragma unroll
        for (int nt8 = 0; nt8 < 8; ++nt8) {
            int nt = wave * 8 + nt8;
            uint4 b0 = *(const uint4*)(wu + ((size_t)(nt * 2 + 0) * 64 + lane) * 8);
            uint4 b1 = *(const uint4*)(wu + ((size_t)(nt * 2 + 1) * 64 + lane) * 8);
            f32x4 a4 = (f32x4){0.f, 0.f, 0.f, 0.f};
            a4 = __builtin_amdgcn_mfma_f32_16x16x32_bf16(af0, __builtin_bit_cast(bf16x8, b0), a4, 0, 0, 0);
            a4 = __builtin_amdgcn_mfma_f32_16x16x32_bf16(af1, __builtin_bit_cast(bf16x8, b1), a4, 0, 0, 0);
            float bu = coeff[1024 + nt * 16 + lanelo];
#pragma unroll
            for (int r = 0; r < 4; ++r) {
                float y = a4[r] + bu;
                a4[r] = y;
                sum[r] += y;
                sq[r] = fmaf(y, y, sq[r]);
            }
            acc8[nt8] = a4;
        }
#pragma unroll
        for (int r = 0; r < 4; ++r) {
#pragma unroll
            for (int m = 1; m <= 8; m <<= 1) {
                sum[r] += __shfl_xor(sum[r], m);
                sq[r] += __shfl_xor(sq[r], m);
            }
        }
        if (lanelo == 0) {
#pragma unroll
            for (int r = 0; r < 4; ++r) {
                postS[quad * 4 + r][wave] = sum[r];
                postQ[quad * 4 + r][wave] = sq[r];
            }
        }
        asm volatile("s_waitcnt lgkmcnt(0)" ::: "memory");
        __builtin_amdgcn_s_barrier();   // post-stat partials visible

        float mean2[4], rstd2[4];
#pragma unroll
        for (int r = 0; r < 4; ++r) {
            int row = quad * 4 + r;
            float4 S = *(const float4*)postS[row];
            float4 Q = *(const float4*)postQ[row];
            float ss = (S.x + S.y) + (S.z + S.w);
            float qq = (Q.x + Q.y) + (Q.z + Q.w);
            mean2[r] = ss * (1.0f / 512.0f);
            float v2 = qq * (1.0f / 512.0f) - mean2[r] * mean2[r];
            rstd2[r] = rsqrtf(v2 + 1e-5f);
        }

        // ---- epilogue: post-LN affine, +x, store ----
        const size_t obase = ((size_t)b * NS + s_base + t * 16) * ND;
#pragma unroll
        for (int nt8 = 0; nt8 < 8; ++nt8) {
            int col = (wave * 8 + nt8) * 16 + lanelo;
            float pw = coeff[col];
            float pb = coeff[512 + col];
#pragma unroll
            for (int r = 0; r < 4; ++r) {
                size_t off = obase + (size_t)(quad * 4 + r) * ND + col;
                out[off] = fmaf((acc8[nt8][r] - mean2[r]) * rstd2[r], pw, pb) + inp[off];
            }
        }
    }
}

// ---------------------------------------------------------------------------
extern "C" void kernel_launch(void* const* d_in, const int* in_sizes, int n_in,
                              void* d_out, int out_size, void* d_ws, size_t ws_size,
                              hipStream_t stream) {
    const float* emb  = (const float*)d_in[0];
    const float* inp  = (const float*)d_in[1];
    const float* dwW  = (const float*)d_in[2];
    const float* dwb  = (const float*)d_in[3];
    const float* dbW  = (const float*)d_in[4];
    const float* dbb  = (const float*)d_in[5];
    const float* uwW  = (const float*)d_in[6];
    const float* uwb  = (const float*)d_in[7];
    const float* ubW  = (const float*)d_in[8];
    const float* ubb  = (const float*)d_in[9];
    const float* pwW  = (const float*)d_in[10];
    const float* pwb  = (const float*)d_in[11];
    const float* pbW  = (const float*)d_in[12];
    const float* pbb  = (const float*)d_in[13];
    const float* powW = (const float*)d_in[14];
    const float* powb = (const float*)d_in[15];
    const float* pobW = (const float*)d_in[16];
    const float* pobb = (const float*)d_in[17];

    unsigned short* wdfrag = (unsigned short*)d_ws;
    unsigned short* wufrag = wdfrag + (size_t)NB * 32768;
    float* vecs = (float*)(wufrag + (size_t)NB * 32768);
    float* cvec = vecs + (size_t)NB * 2624;

    hyper_vec<<<(NB * 2624 + 255) / 256, 256, 0, stream>>>(
        emb, pwW, pwb, pbW, pbb, powW, powb, pobW, pobb, ubW, ubb, dbW, dbb, vecs);
    hipMemsetAsync(cvec, 0, (size_t)NB * 128 * sizeof(float), stream);
    hyper_pack<<<512, 256, 0, stream>>>(emb, dwW, dwb, uwW, uwb, vecs,
                                        wdfrag, wufrag, cvec);
    fused_adapter<<<NB * (NS / 64), 256, 0, stream>>>(
        inp, wdfrag, wufrag, vecs, cvec, (float*)d_out);
}

// Round 3
// 393.028 us; speedup vs baseline: 1.0768x; 1.0768x over previous
//
#include <hip/hip_runtime.h>

#define NB 32
#define NS 2048
#define ND 512
#define NA 64
#define NE 64

typedef __bf16 bf16x8 __attribute__((ext_vector_type(8)));
typedef float f32x4 __attribute__((ext_vector_type(4)));

__device__ __forceinline__ unsigned short f2bf(float f) {
    union { float f; unsigned u; } v; v.f = f;
    unsigned r = (v.u + 0x7fffu + ((v.u >> 16) & 1u)) >> 16;
    return (unsigned short)r;
}
__device__ __forceinline__ unsigned pk(float a, float b) {
    return (unsigned)f2bf(a) | ((unsigned)f2bf(b) << 16);
}

// raw barrier: LDS-drain + barrier, but vmcnt stays OUTSTANDING (prefetch
// survives across phases). Empirically validated (round 2 passed with it).
#define BAR() do { asm volatile("s_waitcnt lgkmcnt(0)" ::: "memory"); \
                   __builtin_amdgcn_s_barrier(); } while (0)

// ---------------------------------------------------------------------------
// Kernel 1b (runs FIRST): the six small per-sample vectors, per b:
// [pre_w 512][pre_b 512][post_w 512][post_b 512][b_up 512][b_down 64] = 2624
// ---------------------------------------------------------------------------
__global__ __launch_bounds__(256) void hyper_vec(
    const float* __restrict__ emb,
    const float* __restrict__ pwW, const float* __restrict__ pwb,
    const float* __restrict__ pbW, const float* __restrict__ pbb,
    const float* __restrict__ powW, const float* __restrict__ powb,
    const float* __restrict__ pobW, const float* __restrict__ pobb,
    const float* __restrict__ ubW, const float* __restrict__ ubb,
    const float* __restrict__ dbW, const float* __restrict__ dbb,
    float* __restrict__ vecs) {
    int gid = blockIdx.x * 256 + threadIdx.x;
    if (gid >= NB * 2624) return;
    int b = gid / 2624;
    int r = gid - b * 2624;
    const float* W; const float* bias; int off, width;
    if (r < 2560) {
        int v = r >> 9; off = r & 511; width = 512;
        switch (v) {
            case 0:  W = pwW;  bias = pwb;  break;
            case 1:  W = pbW;  bias = pbb;  break;
            case 2:  W = powW; bias = powb; break;
            case 3:  W = pobW; bias = pobb; break;
            default: W = ubW;  bias = ubb;  break;
        }
    } else {
        off = r - 2560; width = 64; W = dbW; bias = dbb;
    }
    float acc = bias[off];
    const float* e = emb + b * 64;
#pragma unroll 8
    for (int k = 0; k < 64; ++k) acc = fmaf(e[k], W[k * width + off], acc);
    vecs[gid] = acc;
}

// ---------------------------------------------------------------------------
// Kernel 1a: hypernet big GEMMs emb[32,64] @ W[64,32768] -> bf16 frags.
// mat==0 (down): fold pre-LN weight in-line (f = raw*pre_w), emit folded
//   frags [b][nt(4)][kc(16)][lane(64)][8] and atomically accumulate
//   c1[b,a]=sum_d raw*pre_b, c2[b,a]=sum_d raw*pre_w into cvec[b][a][2].
// mat==1 (up): frags [b][nblk(32)][kch(2)][lane(64)][8].
// ---------------------------------------------------------------------------
__global__ __launch_bounds__(256) void hyper_pack(
    const float* __restrict__ emb,
    const float* __restrict__ dwW, const float* __restrict__ dwb,
    const float* __restrict__ uwW, const float* __restrict__ uwb,
    const float* __restrict__ vecs,
    unsigned short* __restrict__ wdfrag, unsigned short* __restrict__ wufrag,
    float* __restrict__ cvec) {
    __shared__ float Wt[64][128];
    __shared__ float embs[NB * NE];
    const int tid = threadIdx.x;
    const int lane = tid & 63;
    const int bx = blockIdx.x;
    const int mat = bx >> 8;
    const int chunk = bx & 255;
    const int base = chunk * 128;
    const int colo = tid & 127;
    const int bh = tid >> 7;            // 0 or 1: b-range [16*bh, 16*bh+16)
    const float* W = mat ? uwW : dwW;
    const float* bias = mat ? uwb : dwb;

    for (int i = tid; i < NB * NE; i += 256) embs[i] = emb[i];
    for (int i = tid; i < 64 * 32; i += 256) {
        int k = i >> 5, c = (i & 31) << 2;
        *(float4*)&Wt[k][c] = *(const float4*)&W[(size_t)k * 32768 + base + c];
    }
    __syncthreads();

    const int col = base + colo;
    const float bv = bias[col];
    float acc[16];
#pragma unroll
    for (int b = 0; b < 16; ++b) acc[b] = bv;

    for (int k0 = 0; k0 < 64; k0 += 4) {
        float w0 = Wt[k0][colo], w1 = Wt[k0 + 1][colo];
        float w2 = Wt[k0 + 2][colo], w3 = Wt[k0 + 3][colo];
#pragma unroll
        for (int b = 0; b < 16; ++b) {
            float4 e = *(const float4*)&embs[(bh * 16 + b) * 64 + k0];
            acc[b] = fmaf(e.x, w0, acc[b]);
            acc[b] = fmaf(e.y, w1, acc[b]);
            acc[b] = fmaf(e.z, w2, acc[b]);
            acc[b] = fmaf(e.w, w3, acc[b]);
        }
    }

    if (mat == 0) {
        int a = col >> 9, d = col & 511;   // a uniform per block (128 | 512)
        size_t idx0 = ((size_t)((a >> 4) * 16 + (d >> 5)) * 64 +
                       (((d & 31) >> 3) * 16 + (a & 15))) * 8 + (d & 7);
#pragma unroll
        for (int b = 0; b < 16; ++b) {
            int bg = bh * 16 + b;
            float raw = acc[b];
            float pw = vecs[bg * 2624 + d];
            float pb = vecs[bg * 2624 + 512 + d];
            float f = raw * pw;
            wdfrag[idx0 + (size_t)bg * 32768] = f2bf(f);
            float c2v = f, c1v = raw * pb;
#pragma unroll
            for (int m = 1; m <= 32; m <<= 1) {
                c2v += __shfl_xor(c2v, m);
                c1v += __shfl_xor(c1v, m);
            }
            if (lane == 0) {
                atomicAdd(&cvec[bg * 128 + 2 * a], c1v);
                atomicAdd(&cvec[bg * 128 + 2 * a + 1], c2v);
            }
        }
    } else {
        int d = col >> 6, a = col & 63;
        size_t idx0 = ((size_t)((d >> 4) * 2 + (a >> 5)) * 64 +
                       (((a & 31) >> 3) * 16 + (d & 15))) * 8 + (a & 7);
#pragma unroll
        for (int b = 0; b < 16; ++b)
            wufrag[idx0 + (size_t)(bh * 16 + b) * 32768] = f2bf(acc[b]);
    }
}

// ---------------------------------------------------------------------------
// Kernel 2: fused [foldedLN + down MFMA] -> relu -> up (MFMA) -> postLN -> +x.
//
// Round-3: pipelined 64-row blocks with the residual held in LDS (f32).
//  * x_lds[16][516] f32: written at stage time, read in the epilogue for the
//    EXACT residual -> inp is read from HBM exactly once, never revisited.
//    This removes the L2-capacity coupling that round 2 exposed (FETCH
//    275 MB when the residual window outgrew the 4 MB/XCD L2).
//  * Tile t+1 lives in 32 VGPRs; its 8 float4 loads are issued one full tile
//    ahead. Raw {lgkmcnt(0); s_barrier} barriers keep them outstanding.
//  * Stats computed from registers at stage time -> preS/preQ[2] (dbuf).
//  * coeff LDS dropped: bu/pw/pb are block-invariant, preloaded to 24 regs.
//  * LDS 53.5 KB -> exactly 3 blocks/CU (LDS-capped; VGPR free to grow).
// Hazards: every LDS buffer's write is >=2 raw barriers after its last read
// (each wave drains lgkmcnt(0) at every barrier); preS/preQ ping-pong.
// ---------------------------------------------------------------------------
__global__ __launch_bounds__(256, 3) void fused_adapter(
    const float* __restrict__ inp,
    const unsigned short* __restrict__ wdfold,
    const unsigned short* __restrict__ wufrag,
    const float* __restrict__ vecs,
    const float* __restrict__ cvec,
    float* __restrict__ out) {
    __shared__ __align__(16) float x_lds[16][516];          // exact residual
    __shared__ __align__(16) unsigned short z_lds[16][520]; // bf16 A-frags
    __shared__ __align__(16) unsigned short mid_lds[16][72];
    __shared__ __align__(16) float preS[2][16][4], preQ[2][16][4];
    __shared__ __align__(16) float postS[16][4], postQ[16][4];

    const int tid = threadIdx.x;
    const int lane = tid & 63;
    const int wave = tid >> 6;
    const int lanelo = lane & 15;
    const int quad = lane >> 4;
    // bijective XCD swizzle: XCD x gets blocks [128x,128x+128) = 4 b's,
    // so that XCD's adapter weights (4 x 128 KB) stay L2-resident.
    const int bx0 = blockIdx.x;
    const int bx = (bx0 & 7) * 128 + (bx0 >> 3);
    const int b = bx >> 5;
    const int s_base = (bx & 31) * 64;   // 64 rows = 4 tiles per block

    const float* vb = vecs + b * 2624;

    // ---- issue tile-0 input loads first (longest latency) ----
    const float* xpw = inp + ((size_t)b * NS + s_base + lanelo) * ND + wave * 128 + quad * 8;
    float4 x0[4], x1[4];
#pragma unroll
    for (int kc2 = 0; kc2 < 4; ++kc2) {
        x0[kc2] = *(const float4*)(xpw + kc2 * 32);
        x1[kc2] = *(const float4*)(xpw + kc2 * 32 + 4);
    }

    // ---- block-invariant coefficients into registers ----
    float bu8[8], pw8[8], pb8[8];
#pragma unroll
    for (int i = 0; i < 8; ++i) {
        int col = (wave * 8 + i) * 16 + lanelo;
        pw8[i] = vb[1024 + col];
        pb8[i] = vb[1536 + col];
        bu8[i] = vb[2048 + col];
    }
    const unsigned short* wd = wdfold + (size_t)b * 32768;
    const unsigned short* wu = wufrag + (size_t)b * 32768;
    const int a_col = wave * 16 + lanelo;
    const float2 cc = *(const float2*)(cvec + b * 128 + 2 * a_col);
    const float c1 = cc.x + vb[2560 + a_col];

    // stage: stats from regs -> preS/Q[buf]; pack bf16 -> z_lds; f32 -> x_lds
    auto stage = [&](int buf) {
        float s = 0.f, q = 0.f;
#pragma unroll
        for (int kc2 = 0; kc2 < 4; ++kc2) {
            float4 a = x0[kc2], c = x1[kc2];
            s += (a.x + a.y + a.z + a.w) + (c.x + c.y + c.z + c.w);
            q = fmaf(a.x, a.x, q); q = fmaf(a.y, a.y, q);
            q = fmaf(a.z, a.z, q); q = fmaf(a.w, a.w, q);
            q = fmaf(c.x, c.x, q); q = fmaf(c.y, c.y, q);
            q = fmaf(c.z, c.z, q); q = fmaf(c.w, c.w, q);
            uint4 au;
            au.x = pk(a.x, a.y); au.y = pk(a.z, a.w);
            au.z = pk(c.x, c.y); au.w = pk(c.z, c.w);
            int col = wave * 128 + kc2 * 32 + quad * 8;
            *(uint4*)&z_lds[lanelo][col] = au;
            *(float4*)&x_lds[lanelo][col] = a;
            *(float4*)&x_lds[lanelo][col + 4] = c;
        }
        s += __shfl_xor(s, 16); s += __shfl_xor(s, 32);
        q += __shfl_xor(q, 16); q += __shfl_xor(q, 32);
        if (lane < 16) { preS[buf][lane][wave] = s; preQ[buf][lane][wave] = q; }
    };
    auto loadx = [&](const float* p) {
#pragma unroll
        for (int kc2 = 0; kc2 < 4; ++kc2) {
            x0[kc2] = *(const float4*)(p + kc2 * 32);
            x1[kc2] = *(const float4*)(p + kc2 * 32 + 4);
        }
    };

    // ---- prologue: stage tile 0, issue tile-1 loads ----
    stage(0);
    loadx(xpw + 16 * ND);
    BAR();   // x_lds/z_lds(t0) + preS/Q[0] visible; tile-1 loads in flight

    for (int t = 0; t < 4; ++t) {
        // ---- pre-LN stats for this tile ----
        float rs[4], mrs[4];
#pragma unroll
        for (int r = 0; r < 4; ++r) {
            int row = quad * 4 + r;
            float4 S = *(const float4*)preS[t & 1][row];
            float4 Q = *(const float4*)preQ[t & 1][row];
            float ss = (S.x + S.y) + (S.z + S.w);
            float qq = (Q.x + Q.y) + (Q.z + Q.w);
            float mean = ss * (1.0f / 512.0f);
            float var = qq * (1.0f / 512.0f) - mean * mean;
            float rstd = rsqrtf(var + 1e-5f);
            rs[r] = rstd;
            mrs[r] = mean * rstd;
        }

        // ---- phase B: down GEMM, nt = wave ----
        f32x4 accd = (f32x4){0.f, 0.f, 0.f, 0.f};
#pragma unroll
        for (int kc = 0; kc < 16; ++kc) {
            uint4 azu = *(const uint4*)&z_lds[lanelo][kc * 32 + quad * 8];
            uint4 bv = *(const uint4*)(wd + ((size_t)(wave * 16 + kc) * 64 + lane) * 8);
            accd = __builtin_amdgcn_mfma_f32_16x16x32_bf16(
                __builtin_bit_cast(bf16x8, azu), __builtin_bit_cast(bf16x8, bv), accd, 0, 0, 0);
        }
#pragma unroll
        for (int r = 0; r < 4; ++r) {
            float v = fmaf(rs[r], accd[r], fmaf(-mrs[r], cc.y, c1));
            mid_lds[quad * 4 + r][a_col] = f2bf(fmaxf(v, 0.0f));
        }
        BAR();   // mid visible

        // ---- phase C: up GEMM, wave w -> cols [128w,128w+128), acc[8] ----
        uint4 a0u = *(const uint4*)&mid_lds[lanelo][quad * 8];
        uint4 a1u = *(const uint4*)&mid_lds[lanelo][32 + quad * 8];
        bf16x8 af0 = __builtin_bit_cast(bf16x8, a0u);
        bf16x8 af1 = __builtin_bit_cast(bf16x8, a1u);
        f32x4 acc8[8];
        float sum[4] = {0.f, 0.f, 0.f, 0.f}, sq[4] = {0.f, 0.f, 0.f, 0.f};
#pragma unroll
        for (int nt8 = 0; nt8 < 8; ++nt8) {
            int nt = wave * 8 + nt8;
            uint4 b0 = *(const uint4*)(wu + ((size_t)(nt * 2 + 0) * 64 + lane) * 8);
            uint4 b1 = *(const uint4*)(wu + ((size_t)(nt * 2 + 1) * 64 + lane) * 8);
            f32x4 a4 = (f32x4){0.f, 0.f, 0.f, 0.f};
            a4 = __builtin_amdgcn_mfma_f32_16x16x32_bf16(af0, __builtin_bit_cast(bf16x8, b0), a4, 0, 0, 0);
            a4 = __builtin_amdgcn_mfma_f32_16x16x32_bf16(af1, __builtin_bit_cast(bf16x8, b1), a4, 0, 0, 0);
            float buv = bu8[nt8];
#pragma unroll
            for (int r = 0; r < 4; ++r) {
                float y = a4[r] + buv;
                a4[r] = y;
                sum[r] += y;
                sq[r] = fmaf(y, y, sq[r]);
            }
            acc8[nt8] = a4;
        }
#pragma unroll
        for (int r = 0; r < 4; ++r) {
#pragma unroll
            for (int m = 1; m <= 8; m <<= 1) {
                sum[r] += __shfl_xor(sum[r], m);
                sq[r] += __shfl_xor(sq[r], m);
            }
        }
        if (lanelo == 0) {
#pragma unroll
            for (int r = 0; r < 4; ++r) {
                postS[quad * 4 + r][wave] = sum[r];
                postQ[quad * 4 + r][wave] = sq[r];
            }
        }
        BAR();   // post-stat partials visible

        float mean2[4], rstd2[4];
#pragma unroll
        for (int r = 0; r < 4; ++r) {
            int row = quad * 4 + r;
            float4 S = *(const float4*)postS[row];
            float4 Q = *(const float4*)postQ[row];
            float ss = (S.x + S.y) + (S.z + S.w);
            float qq = (Q.x + Q.y) + (Q.z + Q.w);
            mean2[r] = ss * (1.0f / 512.0f);
            float v2 = qq * (1.0f / 512.0f) - mean2[r] * mean2[r];
            rstd2[r] = rsqrtf(v2 + 1e-5f);
        }

        // ---- epilogue: post-LN affine + exact LDS residual + store ----
        const size_t obase = ((size_t)b * NS + s_base + t * 16) * ND;
#pragma unroll
        for (int nt8 = 0; nt8 < 8; ++nt8) {
            int col = (wave * 8 + nt8) * 16 + lanelo;
#pragma unroll
            for (int r = 0; r < 4; ++r) {
                size_t off = obase + (size_t)(quad * 4 + r) * ND + col;
                float xres = x_lds[quad * 4 + r][col];
                out[off] = fmaf((acc8[nt8][r] - mean2[r]) * rstd2[r],
                                pw8[nt8], pb8[nt8]) + xres;
            }
        }
        BAR();   // all x_lds/z_lds reads of tile t done -> safe to overwrite

        if (t < 3) {
            stage((t + 1) & 1);                       // consume prefetched regs
            if (t < 2) loadx(xpw + (size_t)(t + 2) * 16 * ND);  // issue t+2
            BAR();   // staged tile t+1 visible
        }
    }
}

// ---------------------------------------------------------------------------
extern "C" void kernel_launch(void* const* d_in, const int* in_sizes, int n_in,
                              void* d_out, int out_size, void* d_ws, size_t ws_size,
                              hipStream_t stream) {
    const float* emb  = (const float*)d_in[0];
    const float* inp  = (const float*)d_in[1];
    const float* dwW  = (const float*)d_in[2];
    const float* dwb  = (const float*)d_in[3];
    const float* dbW  = (const float*)d_in[4];
    const float* dbb  = (const float*)d_in[5];
    const float* uwW  = (const float*)d_in[6];
    const float* uwb  = (const float*)d_in[7];
    const float* ubW  = (const float*)d_in[8];
    const float* ubb  = (const float*)d_in[9];
    const float* pwW  = (const float*)d_in[10];
    const float* pwb  = (const float*)d_in[11];
    const float* pbW  = (const float*)d_in[12];
    const float* pbb  = (const float*)d_in[13];
    const float* powW = (const float*)d_in[14];
    const float* powb = (const float*)d_in[15];
    const float* pobW = (const float*)d_in[16];
    const float* pobb = (const float*)d_in[17];

    unsigned short* wdfrag = (unsigned short*)d_ws;
    unsigned short* wufrag = wdfrag + (size_t)NB * 32768;
    float* vecs = (float*)(wufrag + (size_t)NB * 32768);
    float* cvec = vecs + (size_t)NB * 2624;

    hyper_vec<<<(NB * 2624 + 255) / 256, 256, 0, stream>>>(
        emb, pwW, pwb, pbW, pbb, powW, powb, pobW, pobb, ubW, ubb, dbW, dbb, vecs);
    hipMemsetAsync(cvec, 0, (size_t)NB * 128 * sizeof(float), stream);
    hyper_pack<<<512, 256, 0, stream>>>(emb, dwW, dwb, uwW, uwb, vecs,
                                        wdfrag, wufrag, cvec);
    fused_adapter<<<NB * (NS / 64), 256, 0, stream>>>(
        inp, wdfrag, wufrag, vecs, cvec, (float*)d_out);
}

// Round 4
// 340.063 us; speedup vs baseline: 1.2445x; 1.1557x over previous
//
#include <hip/hip_runtime.h>

#define NB 32
#define NS 2048
#define ND 512
#define NA 64
#define NE 64

typedef __bf16 bf16x8 __attribute__((ext_vector_type(8)));
typedef float f32x4 __attribute__((ext_vector_type(4)));

__device__ __forceinline__ unsigned short f2bf(float f) {
    union { float f; unsigned u; } v; v.f = f;
    unsigned r = (v.u + 0x7fffu + ((v.u >> 16) & 1u)) >> 16;
    return (unsigned short)r;
}
__device__ __forceinline__ unsigned pk(float a, float b) {
    return (unsigned)f2bf(a) | ((unsigned)f2bf(b) << 16);
}

// raw barrier: LDS-drain + barrier; vmcnt stays OUTSTANDING so pre-issued
// global loads survive across phases. Correctness validated (R2/R3 passed).
#define BAR() do { asm volatile("s_waitcnt lgkmcnt(0)" ::: "memory"); \
                   __builtin_amdgcn_s_barrier(); } while (0)

// ---------------------------------------------------------------------------
// Kernel 1b (runs FIRST): the six small per-sample vectors, per b:
// [pre_w 512][pre_b 512][post_w 512][post_b 512][b_up 512][b_down 64] = 2624
// ---------------------------------------------------------------------------
__global__ __launch_bounds__(256) void hyper_vec(
    const float* __restrict__ emb,
    const float* __restrict__ pwW, const float* __restrict__ pwb,
    const float* __restrict__ pbW, const float* __restrict__ pbb,
    const float* __restrict__ powW, const float* __restrict__ powb,
    const float* __restrict__ pobW, const float* __restrict__ pobb,
    const float* __restrict__ ubW, const float* __restrict__ ubb,
    const float* __restrict__ dbW, const float* __restrict__ dbb,
    float* __restrict__ vecs) {
    int gid = blockIdx.x * 256 + threadIdx.x;
    if (gid >= NB * 2624) return;
    int b = gid / 2624;
    int r = gid - b * 2624;
    const float* W; const float* bias; int off, width;
    if (r < 2560) {
        int v = r >> 9; off = r & 511; width = 512;
        switch (v) {
            case 0:  W = pwW;  bias = pwb;  break;
            case 1:  W = pbW;  bias = pbb;  break;
            case 2:  W = powW; bias = powb; break;
            case 3:  W = pobW; bias = pobb; break;
            default: W = ubW;  bias = ubb;  break;
        }
    } else {
        off = r - 2560; width = 64; W = dbW; bias = dbb;
    }
    float acc = bias[off];
    const float* e = emb + b * 64;
#pragma unroll 8
    for (int k = 0; k < 64; ++k) acc = fmaf(e[k], W[k * width + off], acc);
    vecs[gid] = acc;
}

// ---------------------------------------------------------------------------
// Kernel 1a: hypernet big GEMMs emb[32,64] @ W[64,32768] -> bf16 frags.
// mat==0 (down): fold pre-LN weight in-line (f = raw*pre_w), emit folded
//   frags [b][nt(4)][kc(16)][lane(64)][8] and atomically accumulate
//   c1[b,a]=sum_d raw*pre_b, c2[b,a]=sum_d raw*pre_w into cvec[b][a][2].
// mat==1 (up): frags [b][nblk(32)][kch(2)][lane(64)][8].
// ---------------------------------------------------------------------------
__global__ __launch_bounds__(256) void hyper_pack(
    const float* __restrict__ emb,
    const float* __restrict__ dwW, const float* __restrict__ dwb,
    const float* __restrict__ uwW, const float* __restrict__ uwb,
    const float* __restrict__ vecs,
    unsigned short* __restrict__ wdfrag, unsigned short* __restrict__ wufrag,
    float* __restrict__ cvec) {
    __shared__ float Wt[64][128];
    __shared__ float embs[NB * NE];
    const int tid = threadIdx.x;
    const int lane = tid & 63;
    const int bx = blockIdx.x;
    const int mat = bx >> 8;
    const int chunk = bx & 255;
    const int base = chunk * 128;
    const int colo = tid & 127;
    const int bh = tid >> 7;            // 0 or 1: b-range [16*bh, 16*bh+16)
    const float* W = mat ? uwW : dwW;
    const float* bias = mat ? uwb : dwb;

    for (int i = tid; i < NB * NE; i += 256) embs[i] = emb[i];
    for (int i = tid; i < 64 * 32; i += 256) {
        int k = i >> 5, c = (i & 31) << 2;
        *(float4*)&Wt[k][c] = *(const float4*)&W[(size_t)k * 32768 + base + c];
    }
    __syncthreads();

    const int col = base + colo;
    const float bv = bias[col];
    float acc[16];
#pragma unroll
    for (int b = 0; b < 16; ++b) acc[b] = bv;

    for (int k0 = 0; k0 < 64; k0 += 4) {
        float w0 = Wt[k0][colo], w1 = Wt[k0 + 1][colo];
        float w2 = Wt[k0 + 2][colo], w3 = Wt[k0 + 3][colo];
#pragma unroll
        for (int b = 0; b < 16; ++b) {
            float4 e = *(const float4*)&embs[(bh * 16 + b) * 64 + k0];
            acc[b] = fmaf(e.x, w0, acc[b]);
            acc[b] = fmaf(e.y, w1, acc[b]);
            acc[b] = fmaf(e.z, w2, acc[b]);
            acc[b] = fmaf(e.w, w3, acc[b]);
        }
    }

    if (mat == 0) {
        int a = col >> 9, d = col & 511;   // a uniform per block (128 | 512)
        size_t idx0 = ((size_t)((a >> 4) * 16 + (d >> 5)) * 64 +
                       (((d & 31) >> 3) * 16 + (a & 15))) * 8 + (d & 7);
#pragma unroll
        for (int b = 0; b < 16; ++b) {
            int bg = bh * 16 + b;
            float raw = acc[b];
            float pw = vecs[bg * 2624 + d];
            float pb = vecs[bg * 2624 + 512 + d];
            float f = raw * pw;
            wdfrag[idx0 + (size_t)bg * 32768] = f2bf(f);
            float c2v = f, c1v = raw * pb;
#pragma unroll
            for (int m = 1; m <= 32; m <<= 1) {
                c2v += __shfl_xor(c2v, m);
                c1v += __shfl_xor(c1v, m);
            }
            if (lane == 0) {
                atomicAdd(&cvec[bg * 128 + 2 * a], c1v);
                atomicAdd(&cvec[bg * 128 + 2 * a + 1], c2v);
            }
        }
    } else {
        int d = col >> 6, a = col & 63;
        size_t idx0 = ((size_t)((d >> 4) * 2 + (a >> 5)) * 64 +
                       (((a & 31) >> 3) * 16 + (d & 15))) * 8 + (a & 7);
#pragma unroll
        for (int b = 0; b < 16; ++b)
            wufrag[idx0 + (size_t)(bh * 16 + b) * 32768] = f2bf(acc[b]);
    }
}

// ---------------------------------------------------------------------------
// Kernel 2: fused [foldedLN + down MFMA] -> relu -> up (MFMA, col-split) ->
// postLN -> +x.  4096 blocks x 256 threads; block = (b, 16-row S-tile).
//
// Round-4 = round-0 datapath (best measured: 100 us) + three bounded changes:
//  (1) bijective XCD swizzle: XCD x owns blocks [512x,512x+512) = 4 b's, so
//      adapter weights (4 x 128 KB) and the epilogue residual re-read stay
//      XCD-L2-local (R1 measured -17 MB FETCH from this).
//  (2) rolling register prefetch of weight fragments: down loop keeps 4
//      loads in flight (bw[4], 16 VGPRs), up loop 2 pairs (bb[2][2], 16
//      VGPRs); initial fills are issued BEFORE the preceding barrier.
//  (3) raw {lgkmcnt(0); s_barrier} barriers so those pre-issued loads stay
//      outstanding across barriers (no vmcnt(0) drain).
// Register budget ~100 < 128 (the 4-waves/SIMD boundary) enforced via
// __launch_bounds__(256,4) -- no spills (R2/R3's failure mode was spill
// traffic, visible as symmetric FETCH/WRITE inflation; WRITE_SIZE is the
// tripwire for this round).
// ---------------------------------------------------------------------------
__global__ __launch_bounds__(256, 4) void fused_adapter(
    const float* __restrict__ inp,
    const unsigned short* __restrict__ wdfold,
    const unsigned short* __restrict__ wufrag,
    const float* __restrict__ vecs,
    const float* __restrict__ cvec,
    float* __restrict__ out) {
    __shared__ __align__(16) unsigned short z_lds[16][520];
    __shared__ __align__(16) unsigned short mid_lds[16][72];
    __shared__ __align__(16) float coeff[1536];  // post_w | post_b | b_up
    __shared__ __align__(16) float preS[16][4], preQ[16][4];
    __shared__ __align__(16) float postS[16][4], postQ[16][4];

    const int tid = threadIdx.x;
    const int lane = tid & 63;
    const int wave = tid >> 6;
    const int lanelo = lane & 15;
    const int quad = lane >> 4;
    // bijective XCD swizzle (4096 % 8 == 0): bx0 % 8 -> XCD; each XCD gets a
    // contiguous 512-block range = 4 complete b's.
    const int bx0 = blockIdx.x;
    const int bx = (bx0 & 7) * 512 + (bx0 >> 3);
    const int b = bx >> 7;
    const int s0 = (bx & 127) * 16;

    const float* vb = vecs + b * 2624;
    for (int i = tid; i < 384; i += 256)
        ((float4*)coeff)[i] = ((const float4*)(vb + 1024))[i];

    // ---- Phase A: wave w loads cols [128w,128w+128) of the 16 rows ----
    const float* xp = inp + ((size_t)b * NS + s0 + lanelo) * ND + wave * 128 + quad * 8;
    float s = 0.f, q = 0.f;
#pragma unroll
    for (int kc2 = 0; kc2 < 4; ++kc2) {
        float4 x0 = *(const float4*)(xp + kc2 * 32);
        float4 x1 = *(const float4*)(xp + kc2 * 32 + 4);
        s += (x0.x + x0.y + x0.z + x0.w) + (x1.x + x1.y + x1.z + x1.w);
        q = fmaf(x0.x, x0.x, q); q = fmaf(x0.y, x0.y, q);
        q = fmaf(x0.z, x0.z, q); q = fmaf(x0.w, x0.w, q);
        q = fmaf(x1.x, x1.x, q); q = fmaf(x1.y, x1.y, q);
        q = fmaf(x1.z, x1.z, q); q = fmaf(x1.w, x1.w, q);
        uint4 au;
        au.x = pk(x0.x, x0.y); au.y = pk(x0.z, x0.w);
        au.z = pk(x1.x, x1.y); au.w = pk(x1.z, x1.w);
        *(uint4*)&z_lds[lanelo][wave * 128 + kc2 * 32 + quad * 8] = au;
    }
    s += __shfl_xor(s, 16); s += __shfl_xor(s, 32);
    q += __shfl_xor(q, 16); q += __shfl_xor(q, 32);
    if (lane < 16) { preS[lane][wave] = s; preQ[lane][wave] = q; }

    // ---- pre-issue weight loads; they stay in flight across BAR() ----
    const unsigned short* wd = wdfold + (size_t)b * 32768;
    const unsigned short* wu = wufrag + (size_t)b * 32768;
    uint4 bw[4];
#pragma unroll
    for (int i = 0; i < 4; ++i)
        bw[i] = *(const uint4*)(wd + ((size_t)(wave * 16 + i) * 64 + lane) * 8);
    uint4 bb[2][2];
#pragma unroll
    for (int i = 0; i < 2; ++i) {
        int nt = wave * 8 + i;
        bb[i][0] = *(const uint4*)(wu + ((size_t)(nt * 2 + 0) * 64 + lane) * 8);
        bb[i][1] = *(const uint4*)(wu + ((size_t)(nt * 2 + 1) * 64 + lane) * 8);
    }
    BAR();  // z + pre-stat partials + coeff visible; weight loads in flight

    float rs[4], mrs[4];
#pragma unroll
    for (int r = 0; r < 4; ++r) {
        int row = quad * 4 + r;
        float4 S = *(const float4*)preS[row];
        float4 Q = *(const float4*)preQ[row];
        float ss = (S.x + S.y) + (S.z + S.w);
        float qq = (Q.x + Q.y) + (Q.z + Q.w);
        float mean = ss * (1.0f / 512.0f);
        float var = qq * (1.0f / 512.0f) - mean * mean;
        float rstd = rsqrtf(var + 1e-5f);
        rs[r] = rstd;
        mrs[r] = mean * rstd;
    }

    // ---- Phase B: down GEMM, nt = wave; rolling 4-deep weight pipeline ----
    f32x4 accd = (f32x4){0.f, 0.f, 0.f, 0.f};
#pragma unroll
    for (int kc = 0; kc < 16; ++kc) {
        uint4 azu = *(const uint4*)&z_lds[lanelo][kc * 32 + quad * 8];
        uint4 bu = bw[kc & 3];
        if (kc < 12)
            bw[kc & 3] = *(const uint4*)(wd + ((size_t)(wave * 16 + kc + 4) * 64 + lane) * 8);
        accd = __builtin_amdgcn_mfma_f32_16x16x32_bf16(
            __builtin_bit_cast(bf16x8, azu), __builtin_bit_cast(bf16x8, bu), accd, 0, 0, 0);
    }
    const int a_col = wave * 16 + lanelo;
    float2 cc = *(const float2*)(cvec + b * 128 + 2 * a_col);
    float c1 = cc.x + vb[2560 + a_col];
#pragma unroll
    for (int r = 0; r < 4; ++r) {
        float v = fmaf(rs[r], accd[r], fmaf(-mrs[r], cc.y, c1));
        mid_lds[quad * 4 + r][a_col] = f2bf(fmaxf(v, 0.0f));
    }
    BAR();  // mid visible; bb[0..1] pairs still in flight

    // ---- Phase C: up GEMM, wave w -> cols [128w,128w+128); rolling 2-pair ----
    uint4 a0u = *(const uint4*)&mid_lds[lanelo][quad * 8];
    uint4 a1u = *(const uint4*)&mid_lds[lanelo][32 + quad * 8];
    bf16x8 af0 = __builtin_bit_cast(bf16x8, a0u);
    bf16x8 af1 = __builtin_bit_cast(bf16x8, a1u);
    f32x4 acc8[8];
    float sum[4] = {0.f, 0.f, 0.f, 0.f}, sq[4] = {0.f, 0.f, 0.f, 0.f};
#pragma unroll
    for (int nt8 = 0; nt8 < 8; ++nt8) {
        int nt = wave * 8 + nt8;
        uint4 b0 = bb[nt8 & 1][0];
        uint4 b1 = bb[nt8 & 1][1];
        if (nt8 < 6) {
            bb[nt8 & 1][0] = *(const uint4*)(wu + ((size_t)((nt + 2) * 2 + 0) * 64 + lane) * 8);
            bb[nt8 & 1][1] = *(const uint4*)(wu + ((size_t)((nt + 2) * 2 + 1) * 64 + lane) * 8);
        }
        f32x4 a4 = (f32x4){0.f, 0.f, 0.f, 0.f};
        a4 = __builtin_amdgcn_mfma_f32_16x16x32_bf16(af0, __builtin_bit_cast(bf16x8, b0), a4, 0, 0, 0);
        a4 = __builtin_amdgcn_mfma_f32_16x16x32_bf16(af1, __builtin_bit_cast(bf16x8, b1), a4, 0, 0, 0);
        float bu = coeff[1024 + nt * 16 + lanelo];
#pragma unroll
        for (int r = 0; r < 4; ++r) {
            float y = a4[r] + bu;
            a4[r] = y;
            sum[r] += y;
            sq[r] = fmaf(y, y, sq[r]);
        }
        acc8[nt8] = a4;
    }
#pragma unroll
    for (int r = 0; r < 4; ++r) {
#pragma unroll
        for (int m = 1; m <= 8; m <<= 1) {
            sum[r] += __shfl_xor(sum[r], m);
            sq[r] += __shfl_xor(sq[r], m);
        }
    }
    if (lanelo == 0) {
#pragma unroll
        for (int r = 0; r < 4; ++r) {
            postS[quad * 4 + r][wave] = sum[r];
            postQ[quad * 4 + r][wave] = sq[r];
        }
    }
    BAR();  // post-stat partials visible

    float mean2[4], rstd2[4];
#pragma unroll
    for (int r = 0; r < 4; ++r) {
        int row = quad * 4 + r;
        float4 S = *(const float4*)postS[row];
        float4 Q = *(const float4*)postQ[row];
        float ss = (S.x + S.y) + (S.z + S.w);
        float qq = (Q.x + Q.y) + (Q.z + Q.w);
        mean2[r] = ss * (1.0f / 512.0f);
        float v2 = qq * (1.0f / 512.0f) - mean2[r] * mean2[r];
        rstd2[r] = rsqrtf(v2 + 1e-5f);
    }

    // ---- epilogue: post-LN affine, +x (L2-local re-read), store ----
    const size_t obase = ((size_t)b * NS + s0) * ND;
#pragma unroll
    for (int nt8 = 0; nt8 < 8; ++nt8) {
        int col = (wave * 8 + nt8) * 16 + lanelo;
        float pw = coeff[col];
        float pb = coeff[512 + col];
#pragma unroll
        for (int r = 0; r < 4; ++r) {
            size_t off = obase + (size_t)(quad * 4 + r) * ND + col;
            out[off] = fmaf((acc8[nt8][r] - mean2[r]) * rstd2[r], pw, pb) + inp[off];
        }
    }
}

// ---------------------------------------------------------------------------
extern "C" void kernel_launch(void* const* d_in, const int* in_sizes, int n_in,
                              void* d_out, int out_size, void* d_ws, size_t ws_size,
                              hipStream_t stream) {
    const float* emb  = (const float*)d_in[0];
    const float* inp  = (const float*)d_in[1];
    const float* dwW  = (const float*)d_in[2];
    const float* dwb  = (const float*)d_in[3];
    const float* dbW  = (const float*)d_in[4];
    const float* dbb  = (const float*)d_in[5];
    const float* uwW  = (const float*)d_in[6];
    const float* uwb  = (const float*)d_in[7];
    const float* ubW  = (const float*)d_in[8];
    const float* ubb  = (const float*)d_in[9];
    const float* pwW  = (const float*)d_in[10];
    const float* pwb  = (const float*)d_in[11];
    const float* pbW  = (const float*)d_in[12];
    const float* pbb  = (const float*)d_in[13];
    const float* powW = (const float*)d_in[14];
    const float* powb = (const float*)d_in[15];
    const float* pobW = (const float*)d_in[16];
    const float* pobb = (const float*)d_in[17];

    unsigned short* wdfrag = (unsigned short*)d_ws;
    unsigned short* wufrag = wdfrag + (size_t)NB * 32768;
    float* vecs = (float*)(wufrag + (size_t)NB * 32768);
    float* cvec = vecs + (size_t)NB * 2624;

    hyper_vec<<<(NB * 2624 + 255) / 256, 256, 0, stream>>>(
        emb, pwW, pwb, pbW, pbb, powW, powb, pobW, pobb, ubW, ubb, dbW, dbb, vecs);
    hipMemsetAsync(cvec, 0, (size_t)NB * 128 * sizeof(float), stream);
    hyper_pack<<<512, 256, 0, stream>>>(emb, dwW, dwb, uwW, uwb, vecs,
                                        wdfrag, wufrag, cvec);
    fused_adapter<<<NB * (NS / 16), 256, 0, stream>>>(
        inp, wdfrag, wufrag, vecs, cvec, (float*)d_out);
}